// Round 1
// baseline (201.631 us; speedup 1.0000x reference)
//
#include <hip/hip_runtime.h>
#include <stdint.h>

typedef __attribute__((ext_vector_type(8))) short  bf16x8;
typedef __attribute__((ext_vector_type(4))) float  f32x4;
typedef __attribute__((ext_vector_type(4))) int    int4v;
typedef __attribute__((ext_vector_type(4))) float  float4v;
typedef __attribute__((ext_vector_type(2))) unsigned int uint2v;

#define NN   8192   // nodes
#define DIN  512
#define DOUT 256

#define MFMA16(a, b, c) __builtin_amdgcn_mfma_f32_16x16x32_bf16((a), (b), (c), 0, 0, 0)

__device__ __forceinline__ unsigned short f2bf(float f) {
  unsigned u = __float_as_uint(f);
  return (unsigned short)((u + 0x7FFFu + ((u >> 16) & 1u)) >> 16);
}

// ---------------------------------------------------------------------------
// Kernel 0: Wt[n][c] = bf16(W[c][n]).  W: [512][256] f32 -> Wt: [256][512] bf16
// ---------------------------------------------------------------------------
__global__ void k_wt(const float* __restrict__ W, unsigned short* __restrict__ Wt) {
  int n = blockIdx.x; // 0..255
  for (int c = threadIdx.x; c < DIN; c += blockDim.x)
    Wt[n * DIN + c] = f2bf(W[c * DOUT + n]);
}

// ---------------------------------------------------------------------------
// Kernel 1: xw_t[n][m] = sum_c x[m][c] * W[c][n]   (bf16 out, transposed)
// grid 128 = 64 m-blocks x 2 n-blocks; block 256 = 4 waves of 64m x 64n
// Fragments direct from global (no LDS, no barriers).
// ---------------------------------------------------------------------------
__global__ __launch_bounds__(256) void k_xwt(const float* __restrict__ x,
                                             const unsigned short* __restrict__ Wt,
                                             unsigned short* __restrict__ xw_t) {
  const int mb = blockIdx.x >> 1, nb = blockIdx.x & 1;
  const int tid = threadIdx.x;
  const int w = tid >> 6, l = tid & 63;
  const int wm = w >> 1, wn = w & 1;
  const int lr = l & 15, lg = l >> 4;
  const int m_base = mb * 128 + wm * 64;
  const int n_base = nb * 128 + wn * 64;

  f32x4 acc[4][4];
  for (int i = 0; i < 4; ++i)
    for (int j = 0; j < 4; ++j) acc[i][j] = (f32x4)0.0f;

  for (int c0 = 0; c0 < DIN; c0 += 32) {
    const int c = c0 + lg * 8;
    bf16x8 af[4], bfv[4];
#pragma unroll
    for (int mt = 0; mt < 4; ++mt) {
      const float* xp = x + (size_t)(m_base + mt * 16 + lr) * DIN + c;
      float4v x0 = *reinterpret_cast<const float4v*>(xp);
      float4v x1 = *reinterpret_cast<const float4v*>(xp + 4);
      bf16x8 a;
#pragma unroll
      for (int j = 0; j < 4; ++j) {
        a[j]     = (short)f2bf(x0[j]);
        a[4 + j] = (short)f2bf(x1[j]);
      }
      af[mt] = a;
    }
#pragma unroll
    for (int nt = 0; nt < 4; ++nt)
      bfv[nt] = *reinterpret_cast<const bf16x8*>(Wt + (size_t)(n_base + nt * 16 + lr) * DIN + c);
#pragma unroll
    for (int mt = 0; mt < 4; ++mt)
#pragma unroll
      for (int nt = 0; nt < 4; ++nt)
        acc[mt][nt] = MFMA16(af[mt], bfv[nt], acc[mt][nt]);
  }

  // epilogue: lane holds C[row=(lg*4+r)][col=lr]; write transposed -> 4
  // consecutive m per lane at fixed n => one 8B store.
#pragma unroll
  for (int nt = 0; nt < 4; ++nt) {
    const int n = n_base + nt * 16 + lr;
#pragma unroll
    for (int mt = 0; mt < 4; ++mt) {
      const int m = m_base + mt * 16 + lg * 4;
      unsigned short b0 = f2bf(acc[mt][nt][0]), b1 = f2bf(acc[mt][nt][1]);
      unsigned short b2 = f2bf(acc[mt][nt][2]), b3 = f2bf(acc[mt][nt][3]);
      uint2v p;
      p[0] = (unsigned)b0 | ((unsigned)b1 << 16);
      p[1] = (unsigned)b2 | ((unsigned)b3 << 16);
      *reinterpret_cast<uint2v*>(xw_t + (size_t)n * NN + m) = p;
    }
  }
}

// ---------------------------------------------------------------------------
// Kernel 2: out[i][n] = (1/deg_i) * sum_j A[i][j] * xw[j][n]
// grid 256 row-blocks of 32 rows (BN = 256 full width -> adj read exactly once
// from HBM). block 512 = 8 waves, each wave: 32 rows x 32 cols.
// adj staged int32->bf16 into double-buffered LDS; deg fused into staging.
// B fragments direct from global xw_t (L2-resident, 4 MB).
// ---------------------------------------------------------------------------
__global__ __launch_bounds__(512) void k_agg(const int* __restrict__ adj,
                                             const unsigned short* __restrict__ xw_t,
                                             float* __restrict__ out) {
  __shared__ unsigned short As[2][32][72]; // 72 = 64 + pad (keeps 16B align: 144B row)
  __shared__ float deg_s[32];

  const int tid = threadIdx.x;
  const int w = tid >> 6, l = tid & 63;
  const int lr = l & 15, lg = l >> 4;
  const int row0 = blockIdx.x * 32;

  // staging: thread -> (row sr, 4 int32 at col sc); same row every iteration
  const int sr = tid >> 4;
  const int sc = (tid & 15) * 4;
  const int* gsrc = adj + (size_t)(row0 + sr) * NN + sc;

  int cnt = 0;
  f32x4 acc[2][2];
  for (int i = 0; i < 2; ++i)
    for (int j = 0; j < 2; ++j) acc[i][j] = (f32x4)0.0f;

  // stage k-tile 0
  {
    int4v v = *reinterpret_cast<const int4v*>(gsrc);
    cnt += v[0] + v[1] + v[2] + v[3];
    unsigned w0 = ((0u - (unsigned)v[0]) & 0x3F80u) | (((0u - (unsigned)v[1]) & 0x3F80u) << 16);
    unsigned w1 = ((0u - (unsigned)v[2]) & 0x3F80u) | (((0u - (unsigned)v[3]) & 0x3F80u) << 16);
    uint2v p; p[0] = w0; p[1] = w1;
    *reinterpret_cast<uint2v*>(&As[0][sr][sc]) = p;
  }
  __syncthreads();

  const int NIT = NN / 64; // 128
  for (int it = 0; it < NIT; ++it) {
    const int cur = it & 1;
    if (it + 1 < NIT) { // prefetch-stage next tile into other buffer
      int4v v = *reinterpret_cast<const int4v*>(gsrc + (size_t)(it + 1) * 64);
      cnt += v[0] + v[1] + v[2] + v[3];
      unsigned w0 = ((0u - (unsigned)v[0]) & 0x3F80u) | (((0u - (unsigned)v[1]) & 0x3F80u) << 16);
      unsigned w1 = ((0u - (unsigned)v[2]) & 0x3F80u) | (((0u - (unsigned)v[3]) & 0x3F80u) << 16);
      uint2v p; p[0] = w0; p[1] = w1;
      *reinterpret_cast<uint2v*>(&As[cur ^ 1][sr][sc]) = p;
    }
    const int k0 = it * 64;
#pragma unroll
    for (int kh = 0; kh < 2; ++kh) {
      bf16x8 a0 = *reinterpret_cast<const bf16x8*>(&As[cur][lr][kh * 32 + lg * 8]);
      bf16x8 a1 = *reinterpret_cast<const bf16x8*>(&As[cur][16 + lr][kh * 32 + lg * 8]);
      const int kk = k0 + kh * 32 + lg * 8;
      bf16x8 b0 = *reinterpret_cast<const bf16x8*>(xw_t + (size_t)(w * 32 + lr) * NN + kk);
      bf16x8 b1 = *reinterpret_cast<const bf16x8*>(xw_t + (size_t)(w * 32 + 16 + lr) * NN + kk);
      acc[0][0] = MFMA16(a0, b0, acc[0][0]);
      acc[0][1] = MFMA16(a0, b1, acc[0][1]);
      acc[1][0] = MFMA16(a1, b0, acc[1][0]);
      acc[1][1] = MFMA16(a1, b1, acc[1][1]);
    }
    __syncthreads();
  }

  // deg: reduce the 16 threads (one 16-lane group) that share row sr
  cnt += __shfl_xor(cnt, 1);
  cnt += __shfl_xor(cnt, 2);
  cnt += __shfl_xor(cnt, 4);
  cnt += __shfl_xor(cnt, 8);
  if ((tid & 15) == 0) deg_s[sr] = (float)cnt;
  __syncthreads();

  float rinv[2][4];
#pragma unroll
  for (int mt = 0; mt < 2; ++mt)
#pragma unroll
    for (int r = 0; r < 4; ++r)
      rinv[mt][r] = 1.0f / deg_s[mt * 16 + lg * 4 + r];

#pragma unroll
  for (int mt = 0; mt < 2; ++mt)
#pragma unroll
    for (int nt = 0; nt < 2; ++nt)
#pragma unroll
      for (int r = 0; r < 4; ++r) {
        const int row = row0 + mt * 16 + lg * 4 + r;
        const int col = w * 32 + nt * 16 + lr;
        out[(size_t)row * DOUT + col] = acc[mt][nt][r] * rinv[mt][r];
      }
}

// ---------------------------------------------------------------------------
extern "C" void kernel_launch(void* const* d_in, const int* in_sizes, int n_in,
                              void* d_out, int out_size, void* d_ws, size_t ws_size,
                              hipStream_t stream) {
  const float* x   = (const float*)d_in[0]; // [8192][512] f32
  const int*   adj = (const int*)d_in[1];   // [8192][8192] i32 (0/1)
  const float* W   = (const float*)d_in[2]; // [512][256] f32
  float* out = (float*)d_out;               // [8192][256] f32

  unsigned short* xw_t = (unsigned short*)d_ws;                          // 256 x 8192 bf16 (4 MB)
  unsigned short* Wt   = (unsigned short*)((char*)d_ws + (size_t)4 * 1024 * 1024); // 256 x 512 bf16

  k_wt<<<256, 128, 0, stream>>>(W, Wt);
  k_xwt<<<128, 256, 0, stream>>>(x, Wt, xw_t);
  k_agg<<<256, 512, 0, stream>>>(adj, xw_t, out);
}